// Round 1
// baseline (5399.217 us; speedup 1.0000x reference)
//
#include <hip/hip_runtime.h>
#include <hip/hip_bf16.h>
#include <math.h>

// ---------------------------------------------------------------------------
// PalaceYiJingBlock — fp32 correctness-first baseline.
// B=2, T=1024, D=1024, H=16, dh=64, Dff=4096 (derived from in_sizes where
// possible; T and H hardcoded per reference setup).
// ---------------------------------------------------------------------------

#define WAVE 64

// ---- block-wide reduction (blockDim.x == 256) -----------------------------
__device__ __forceinline__ float block_reduce_sum(float v, float* sbuf) {
    for (int off = 32; off; off >>= 1) v += __shfl_down(v, off);
    int lane = threadIdx.x & 63, wid = threadIdx.x >> 6;
    if (lane == 0) sbuf[wid] = v;
    __syncthreads();
    float r = sbuf[0] + sbuf[1] + sbuf[2] + sbuf[3];
    __syncthreads();
    return r;
}

__device__ __forceinline__ float block_reduce_max(float v, float* sbuf) {
    for (int off = 32; off; off >>= 1) v = fmaxf(v, __shfl_down(v, off));
    int lane = threadIdx.x & 63, wid = threadIdx.x >> 6;
    if (lane == 0) sbuf[wid] = v;
    __syncthreads();
    float r = fmaxf(fmaxf(sbuf[0], sbuf[1]), fmaxf(sbuf[2], sbuf[3]));
    __syncthreads();
    return r;
}

// ---- LayerNorm: one block per row, D multiple of 1024 ---------------------
__global__ __launch_bounds__(256) void ln_kernel(
    const float* __restrict__ x, const float* __restrict__ g,
    const float* __restrict__ b, float* __restrict__ out, int D)
{
    __shared__ float sbuf[4];
    __shared__ float stats[2];
    int row = blockIdx.x;
    const float4* xr = (const float4*)(x + (size_t)row * D);
    float4* orow = (float4*)(out + (size_t)row * D);
    int tid = threadIdx.x;
    int n4 = D >> 2;
    float sum = 0.f, sumsq = 0.f;
    for (int i = tid; i < n4; i += 256) {
        float4 v = xr[i];
        sum += v.x + v.y + v.z + v.w;
        sumsq += v.x * v.x + v.y * v.y + v.z * v.z + v.w * v.w;
    }
    float ts = block_reduce_sum(sum, sbuf);
    float tq = block_reduce_sum(sumsq, sbuf);
    if (tid == 0) {
        float m = ts / (float)D;
        float var = tq / (float)D - m * m;
        stats[0] = m;
        stats[1] = rsqrtf(var + 1e-5f);
    }
    __syncthreads();
    float m = stats[0], r = stats[1];
    const float4* gv = (const float4*)g;
    const float4* bv = (const float4*)b;
    for (int i = tid; i < n4; i += 256) {
        float4 v = xr[i];
        float4 gg = gv[i];
        float4 bb = bv[i];
        float4 o;
        o.x = (v.x - m) * r * gg.x + bb.x;
        o.y = (v.y - m) * r * gg.y + bb.y;
        o.z = (v.z - m) * r * gg.z + bb.z;
        o.w = (v.w - m) * r * gg.w + bb.w;
        orow[i] = o;
    }
}

// ---- generic fp32 GEMM: C = act(A@W + bias) + resid -----------------------
// A [M,K], W [K,N], row-major. M%64==0, N%64==0, K%16==0.
// act: 0 = none, 1 = exact GELU.
#define TM 64
#define TN 64
#define TK 16
__global__ __launch_bounds__(256) void gemm_kernel(
    const float* __restrict__ A, const float* __restrict__ W,
    const float* __restrict__ bias, const float* __restrict__ resid,
    float* __restrict__ C, int M, int N, int K, int act)
{
    __shared__ float As[TK][TM + 1];
    __shared__ float Ws[TK][TN + 1];
    int bm = blockIdx.y * TM;
    int bn = blockIdx.x * TN;
    int tid = threadIdx.x;
    int tx = tid & 15;   // n group
    int ty = tid >> 4;   // m group
    float acc[4][4] = {{0.f}};
    for (int k0 = 0; k0 < K; k0 += TK) {
        #pragma unroll
        for (int i = 0; i < 4; ++i) {
            int e = tid + 256 * i;
            int r = e >> 4, c = e & 15;
            As[c][r] = A[(size_t)(bm + r) * K + k0 + c];
        }
        #pragma unroll
        for (int i = 0; i < 4; ++i) {
            int e = tid + 256 * i;
            int kk = e >> 6, n = e & 63;
            Ws[kk][n] = W[(size_t)(k0 + kk) * N + bn + n];
        }
        __syncthreads();
        #pragma unroll
        for (int kk = 0; kk < TK; ++kk) {
            float a[4], w[4];
            #pragma unroll
            for (int i = 0; i < 4; ++i) a[i] = As[kk][ty * 4 + i];
            #pragma unroll
            for (int j = 0; j < 4; ++j) w[j] = Ws[kk][tx * 4 + j];
            #pragma unroll
            for (int i = 0; i < 4; ++i)
                #pragma unroll
                for (int j = 0; j < 4; ++j)
                    acc[i][j] += a[i] * w[j];
        }
        __syncthreads();
    }
    #pragma unroll
    for (int i = 0; i < 4; ++i) {
        int row = bm + ty * 4 + i;
        #pragma unroll
        for (int j = 0; j < 4; ++j) {
            int col = bn + tx * 4 + j;
            float val = acc[i][j];
            if (bias) val += bias[col];
            if (act == 1) val = 0.5f * val * (1.0f + erff(val * 0.70710678118654752f));
            if (resid) val += resid[(size_t)row * N + col];
            C[(size_t)row * N + col] = val;
        }
    }
}

// ---- palace attention: one block per (b,h,t); T=1024, dh=64 ---------------
__global__ __launch_bounds__(256) void attn_kernel(
    const float* __restrict__ q, const float* __restrict__ k,
    const float* __restrict__ v, const float* __restrict__ inter_w,
    float* __restrict__ ao, int T, int H, int dh)
{
    __shared__ float sbuf[4];
    __shared__ float qs[64];
    __shared__ float sc[1024];
    __shared__ float part[4][64];
    int t = blockIdx.x, h = blockIdx.y, b = blockIdx.z;
    int D = H * dh;
    int tid = threadIdx.x;
    const float* qrow = q + (size_t)(b * T + t) * D + h * dh;
    if (tid < 64) qs[tid] = qrow[tid];
    __syncthreads();
    float scale = rsqrtf((float)dh);
    for (int s = tid; s < T; s += 256) {
        const float* krow = k + (size_t)(b * T + s) * D + h * dh;
        float acc = 0.f;
        #pragma unroll
        for (int d = 0; d < 64; d += 4) {
            float4 kv = *(const float4*)(krow + d);
            acc += qs[d] * kv.x + qs[d + 1] * kv.y + qs[d + 2] * kv.z + qs[d + 3] * kv.w;
        }
        sc[s] = acc * scale;
    }
    __syncthreads();
    float lmax = -INFINITY;
    for (int s = tid; s < T; s += 256) lmax = fmaxf(lmax, sc[s]);
    float gmax = block_reduce_max(lmax, sbuf);
    float lsum = 0.f;
    for (int s = tid; s < T; s += 256) {
        float e = __expf(sc[s] - gmax);
        sc[s] = e;
        lsum += e;
    }
    float gsum = block_reduce_sum(lsum, sbuf);
    float inv = 1.0f / gsum;
    float sw = 1.0f / (1.0f + __expf(-inter_w[0]));
    int palt = (t & 63) >> 3;
    for (int s = tid; s < T; s += 256) {
        float mv = (((s & 63) >> 3) == palt) ? 1.0f : sw;
        sc[s] *= inv * mv;
    }
    __syncthreads();
    // accumulate over v: tid = d + 64*c
    int d = tid & 63, c = tid >> 6;
    int chunk = T >> 2;
    float acc = 0.f;
    const float* vb = v + (size_t)b * T * D + h * dh + d;
    for (int s = c * chunk; s < (c + 1) * chunk; ++s)
        acc += sc[s] * vb[(size_t)s * D];
    part[c][d] = acc;
    __syncthreads();
    if (tid < 64) {
        float r = part[0][tid] + part[1][tid] + part[2][tid] + part[3][tid];
        ao[(size_t)(b * T + t) * D + h * dh + tid] = r;
    }
}

// ---- GAT src/dst coefficients: one block per row --------------------------
__global__ __launch_bounds__(256) void gat_coeff_kernel(
    const float* __restrict__ hw, const float* __restrict__ a_src,
    const float* __restrict__ a_dst, float* __restrict__ sc,
    float* __restrict__ tc, int D)
{
    __shared__ float sbuf[4];
    int row = blockIdx.x;
    const float* hr = hw + (size_t)row * D;
    float s1 = 0.f, s2 = 0.f;
    for (int i = threadIdx.x; i < D; i += 256) {
        float h = hr[i];
        s1 += h * a_src[i];
        s2 += h * a_dst[i];
    }
    float t1 = block_reduce_sum(s1, sbuf);
    float t2 = block_reduce_sum(s2, sbuf);
    if (threadIdx.x == 0) { sc[row] = t1; tc[row] = t2; }
}

// ---- GAT aggregate: one block per (b,t); T=1024, D=1024 -------------------
__global__ __launch_bounds__(256) void gat_agg_kernel(
    const float* __restrict__ hw, const float* __restrict__ sc,
    const float* __restrict__ tc, float* __restrict__ hg, int T, int D)
{
    __shared__ float sbuf[4];
    __shared__ float w[1024];
    int t = blockIdx.x, b = blockIdx.y;
    int tid = threadIdx.x;
    float scv = sc[b * T + t];
    float lmax = -INFINITY;
    for (int s = tid; s < T; s += 256) {
        float e = scv + tc[b * T + s];
        e = e > 0.f ? e : 0.2f * e;
        w[s] = e;
        lmax = fmaxf(lmax, e);
    }
    float gmax = block_reduce_max(lmax, sbuf);
    float lsum = 0.f;
    for (int s = tid; s < T; s += 256) {
        float e = __expf(w[s] - gmax);
        w[s] = e;
        lsum += e;
    }
    float gsum = block_reduce_sum(lsum, sbuf);
    float inv = 1.0f / gsum;
    for (int s = tid; s < T; s += 256) w[s] *= inv;
    __syncthreads();
    const float* hwb = hw + (size_t)b * T * D;
    int d0 = tid * 4;
    float4 acc = {0.f, 0.f, 0.f, 0.f};
    for (int s = 0; s < T; ++s) {
        float ws = w[s];
        float4 hv = *(const float4*)(hwb + (size_t)s * D + d0);
        acc.x += ws * hv.x;
        acc.y += ws * hv.y;
        acc.z += ws * hv.z;
        acc.w += ws * hv.w;
    }
    *(float4*)(hg + (size_t)(b * T + t) * D + d0) = acc;
}

// ---- gated fusion: x2 = x + a*hp + (1-a)*hg -------------------------------
__global__ __launch_bounds__(256) void fuse_kernel(
    const float4* __restrict__ x, const float4* __restrict__ hp,
    const float4* __restrict__ hg, const float* __restrict__ gate,
    float4* __restrict__ x2, int n4)
{
    int i = blockIdx.x * 256 + threadIdx.x;
    if (i >= n4) return;
    float a = 1.0f / (1.0f + __expf(-gate[0]));
    float one_m = 1.0f - a;
    float4 xv = x[i], pv = hp[i], gv = hg[i];
    float4 o;
    o.x = xv.x + a * pv.x + one_m * gv.x;
    o.y = xv.y + a * pv.y + one_m * gv.y;
    o.z = xv.z + a * pv.z + one_m * gv.z;
    o.w = xv.w + a * pv.w + one_m * gv.w;
    x2[i] = o;
}

// ---------------------------------------------------------------------------
extern "C" void kernel_launch(void* const* d_in, const int* in_sizes, int n_in,
                              void* d_out, int out_size, void* d_ws, size_t ws_size,
                              hipStream_t stream) {
    const float* x      = (const float*)d_in[0];
    const float* Wq     = (const float*)d_in[1];
    const float* bq     = (const float*)d_in[2];
    const float* Wk     = (const float*)d_in[3];
    const float* bk     = (const float*)d_in[4];
    const float* Wv     = (const float*)d_in[5];
    const float* bv     = (const float*)d_in[6];
    const float* Wo     = (const float*)d_in[7];
    const float* bo     = (const float*)d_in[8];
    const float* interw = (const float*)d_in[9];
    const float* Wg     = (const float*)d_in[10];
    const float* a_src  = (const float*)d_in[11];
    const float* a_dst  = (const float*)d_in[12];
    const float* g1     = (const float*)d_in[13];
    const float* b1     = (const float*)d_in[14];
    const float* g2     = (const float*)d_in[15];
    const float* b2     = (const float*)d_in[16];
    const float* g3     = (const float*)d_in[17];
    const float* b3     = (const float*)d_in[18];
    const float* gate   = (const float*)d_in[19];
    const float* W1     = (const float*)d_in[20];
    const float* bf1    = (const float*)d_in[21];
    const float* W2     = (const float*)d_in[22];
    const float* bf2    = (const float*)d_in[23];

    const int D   = in_sizes[2];           // 1024
    const int BT  = in_sizes[0] / D;       // 2048
    const int T   = 1024;
    const int B   = BT / T;                // 2
    const int H   = 16;
    const int dh  = D / H;                 // 64
    const int Dff = in_sizes[21];          // 4096

    float* ws = (float*)d_ws;
    const size_t SL = (size_t)BT * D;      // 2M floats per slot
    float* h1  = ws + 0 * SL;
    float* h2  = ws + 1 * SL;
    float* qb  = ws + 2 * SL;
    float* kb  = ws + 3 * SL;
    float* vb  = ws + 4 * SL;
    float* ao  = ws + 5 * SL;
    float* hp  = ws + 2 * SL;              // overwrites q (dead after attn)
    float* hw  = ws + 3 * SL;              // overwrites k
    float* hg  = ws + 4 * SL;              // overwrites v
    float* x2  = ws + 0 * SL;              // overwrites h1
    float* hf  = ws + 1 * SL;              // overwrites h2
    float* mid = ws + 2 * SL;              // spans slots 2..5 (BT*Dff floats)
    float* scb = ws + 6 * SL;
    float* tcb = scb + BT;

    dim3 blk(256);
    dim3 gD(D / TN, BT / TM);
    dim3 gF(Dff / TN, BT / TM);

    // LN branches
    ln_kernel<<<BT, blk, 0, stream>>>(x, g1, b1, h1, D);
    ln_kernel<<<BT, blk, 0, stream>>>(x, g2, b2, h2, D);

    // QKV projections
    gemm_kernel<<<gD, blk, 0, stream>>>(h1, Wq, bq, nullptr, qb, BT, D, D, 0);
    gemm_kernel<<<gD, blk, 0, stream>>>(h1, Wk, bk, nullptr, kb, BT, D, D, 0);
    gemm_kernel<<<gD, blk, 0, stream>>>(h1, Wv, bv, nullptr, vb, BT, D, D, 0);

    // palace attention
    attn_kernel<<<dim3(T, H, B), blk, 0, stream>>>(qb, kb, vb, interw, ao, T, H, dh);
    gemm_kernel<<<gD, blk, 0, stream>>>(ao, Wo, bo, nullptr, hp, BT, D, D, 0);

    // GAT branch
    gemm_kernel<<<gD, blk, 0, stream>>>(h2, Wg, nullptr, nullptr, hw, BT, D, D, 0);
    gat_coeff_kernel<<<BT, blk, 0, stream>>>(hw, a_src, a_dst, scb, tcb, D);
    gat_agg_kernel<<<dim3(T, B), blk, 0, stream>>>(hw, scb, tcb, hg, T, D);

    // gated fusion + FFN
    int n4 = (int)(SL >> 2);
    fuse_kernel<<<(n4 + 255) / 256, blk, 0, stream>>>(
        (const float4*)x, (const float4*)hp, (const float4*)hg, gate, (float4*)x2, n4);
    ln_kernel<<<BT, blk, 0, stream>>>(x2, g3, b3, hf, D);
    gemm_kernel<<<gF, blk, 0, stream>>>(hf, W1, bf1, nullptr, mid, BT, Dff, D, 1);
    gemm_kernel<<<gD, blk, 0, stream>>>(mid, W2, bf2, x2, (float*)d_out, BT, D, Dff, 0);
}

// Round 2
// 1707.967 us; speedup vs baseline: 3.1612x; 3.1612x over previous
//
#include <hip/hip_runtime.h>
#include <hip/hip_bf16.h>
#include <math.h>

// ---------------------------------------------------------------------------
// PalaceYiJingBlock — round 1: flash-style palace attention + tiled GAT.
// B=2, T=1024, D=1024, H=16, dh=64, Dff=4096.
// ---------------------------------------------------------------------------

// ---- block-wide reduction (blockDim.x == 256) -----------------------------
__device__ __forceinline__ float block_reduce_sum(float v, float* sbuf) {
    for (int off = 32; off; off >>= 1) v += __shfl_down(v, off);
    int lane = threadIdx.x & 63, wid = threadIdx.x >> 6;
    if (lane == 0) sbuf[wid] = v;
    __syncthreads();
    float r = sbuf[0] + sbuf[1] + sbuf[2] + sbuf[3];
    __syncthreads();
    return r;
}

// ---- LayerNorm: one block per row -----------------------------------------
__global__ __launch_bounds__(256) void ln_kernel(
    const float* __restrict__ x, const float* __restrict__ g,
    const float* __restrict__ b, float* __restrict__ out, int D)
{
    __shared__ float sbuf[4];
    __shared__ float stats[2];
    int row = blockIdx.x;
    const float4* xr = (const float4*)(x + (size_t)row * D);
    float4* orow = (float4*)(out + (size_t)row * D);
    int tid = threadIdx.x;
    int n4 = D >> 2;
    float sum = 0.f, sumsq = 0.f;
    for (int i = tid; i < n4; i += 256) {
        float4 v = xr[i];
        sum += v.x + v.y + v.z + v.w;
        sumsq += v.x * v.x + v.y * v.y + v.z * v.z + v.w * v.w;
    }
    float ts = block_reduce_sum(sum, sbuf);
    float tq = block_reduce_sum(sumsq, sbuf);
    if (tid == 0) {
        float m = ts / (float)D;
        float var = tq / (float)D - m * m;
        stats[0] = m;
        stats[1] = rsqrtf(var + 1e-5f);
    }
    __syncthreads();
    float m = stats[0], r = stats[1];
    const float4* gv = (const float4*)g;
    const float4* bv = (const float4*)b;
    for (int i = tid; i < n4; i += 256) {
        float4 v = xr[i];
        float4 gg = gv[i];
        float4 bb = bv[i];
        float4 o;
        o.x = (v.x - m) * r * gg.x + bb.x;
        o.y = (v.y - m) * r * gg.y + bb.y;
        o.z = (v.z - m) * r * gg.z + bb.z;
        o.w = (v.w - m) * r * gg.w + bb.w;
        orow[i] = o;
    }
}

// ---- generic fp32 GEMM: C = act(A@W + bias) + resid -----------------------
#define TM 64
#define TN 64
#define TK 16
__global__ __launch_bounds__(256) void gemm_kernel(
    const float* __restrict__ A, const float* __restrict__ W,
    const float* __restrict__ bias, const float* __restrict__ resid,
    float* __restrict__ C, int M, int N, int K, int act)
{
    __shared__ float As[TK][TM + 1];
    __shared__ float Ws[TK][TN + 1];
    int bm = blockIdx.y * TM;
    int bn = blockIdx.x * TN;
    int tid = threadIdx.x;
    int tx = tid & 15;
    int ty = tid >> 4;
    float acc[4][4] = {{0.f}};
    for (int k0 = 0; k0 < K; k0 += TK) {
        #pragma unroll
        for (int i = 0; i < 4; ++i) {
            int e = tid + 256 * i;
            int r = e >> 4, c = e & 15;
            As[c][r] = A[(size_t)(bm + r) * K + k0 + c];
        }
        #pragma unroll
        for (int i = 0; i < 4; ++i) {
            int e = tid + 256 * i;
            int kk = e >> 6, n = e & 63;
            Ws[kk][n] = W[(size_t)(k0 + kk) * N + bn + n];
        }
        __syncthreads();
        #pragma unroll
        for (int kk = 0; kk < TK; ++kk) {
            float a[4], w[4];
            #pragma unroll
            for (int i = 0; i < 4; ++i) a[i] = As[kk][ty * 4 + i];
            #pragma unroll
            for (int j = 0; j < 4; ++j) w[j] = Ws[kk][tx * 4 + j];
            #pragma unroll
            for (int i = 0; i < 4; ++i)
                #pragma unroll
                for (int j = 0; j < 4; ++j)
                    acc[i][j] += a[i] * w[j];
        }
        __syncthreads();
    }
    #pragma unroll
    for (int i = 0; i < 4; ++i) {
        int row = bm + ty * 4 + i;
        #pragma unroll
        for (int j = 0; j < 4; ++j) {
            int col = bn + tx * 4 + j;
            float val = acc[i][j];
            if (bias) val += bias[col];
            if (act == 1) val = 0.5f * val * (1.0f + erff(val * 0.70710678118654752f));
            if (resid) val += resid[(size_t)row * N + col];
            C[(size_t)row * N + col] = val;
        }
    }
}

// ---- flash-style palace attention -----------------------------------------
// grid (T/64, H, B), block 256. Q tile 64 rows resident; K/V time-share one
// LDS buffer. Online softmax; palace mask (block-diag 8x8 within 64-tile)
// applied post-exp, excluded from the denominator.
__global__ __launch_bounds__(256) void attn_flash_kernel(
    const float* __restrict__ q, const float* __restrict__ k,
    const float* __restrict__ v, const float* __restrict__ inter_w,
    float* __restrict__ ao, int T, int H)
{
    __shared__ float Qs[64][65];
    __shared__ float KV[64][65];
    __shared__ float Ss[64][65];

    int t0 = blockIdx.x * 64;
    int h = blockIdx.y, b = blockIdx.z;
    int D = H * 64;
    int tid = threadIdx.x;
    int tx = tid & 15, ty = tid >> 4;
    float sw = 1.0f / (1.0f + __expf(-inter_w[0]));

    const float* qbase = q + (size_t)(b * T + t0) * D + h * 64;
    const float* kbase = k + (size_t)(b * T) * D + h * 64;
    const float* vbase = v + (size_t)(b * T) * D + h * 64;

    #pragma unroll
    for (int i = 0; i < 16; ++i) {
        int e = tid + 256 * i;
        int r = e >> 6, d = e & 63;
        Qs[r][d] = qbase[(size_t)r * D + d] * 0.125f;   // fold 1/sqrt(64)
    }

    float acc[4][4] = {{0.f}};
    float mrow[4] = {-1e30f, -1e30f, -1e30f, -1e30f};
    float lrow[4] = {0.f, 0.f, 0.f, 0.f};

    for (int s0 = 0; s0 < T; s0 += 64) {
        __syncthreads();           // prev PV done: KV + Ss reusable
        #pragma unroll
        for (int i = 0; i < 16; ++i) {
            int e = tid + 256 * i;
            int r = e >> 6, d = e & 63;
            KV[r][d] = kbase[(size_t)(s0 + r) * D + d];
        }
        __syncthreads();
        // S = Q @ K^T, 4x4 per thread
        float s[4][4] = {{0.f}};
        #pragma unroll 8
        for (int d = 0; d < 64; ++d) {
            float a[4], bb[4];
            #pragma unroll
            for (int i = 0; i < 4; ++i) a[i] = Qs[ty * 4 + i][d];
            #pragma unroll
            for (int j = 0; j < 4; ++j) bb[j] = KV[tx * 4 + j][d];
            #pragma unroll
            for (int i = 0; i < 4; ++i)
                #pragma unroll
                for (int j = 0; j < 4; ++j)
                    s[i][j] += a[i] * bb[j];
        }
        // online softmax + palace mask
        #pragma unroll
        for (int i = 0; i < 4; ++i) {
            int row = ty * 4 + i;
            float rm = fmaxf(fmaxf(s[i][0], s[i][1]), fmaxf(s[i][2], s[i][3]));
            rm = fmaxf(rm, __shfl_xor(rm, 1));
            rm = fmaxf(rm, __shfl_xor(rm, 2));
            rm = fmaxf(rm, __shfl_xor(rm, 4));
            rm = fmaxf(rm, __shfl_xor(rm, 8));
            float mnew = fmaxf(mrow[i], rm);
            float resc = __expf(mrow[i] - mnew);
            mrow[i] = mnew;
            #pragma unroll
            for (int j = 0; j < 4; ++j) acc[i][j] *= resc;
            float rs = 0.f;
            float p[4];
            #pragma unroll
            for (int j = 0; j < 4; ++j) {
                p[j] = __expf(s[i][j] - mnew);
                rs += p[j];
            }
            rs += __shfl_xor(rs, 1);
            rs += __shfl_xor(rs, 2);
            rs += __shfl_xor(rs, 4);
            rs += __shfl_xor(rs, 8);
            lrow[i] = lrow[i] * resc + rs;
            int pr = row >> 3;
            #pragma unroll
            for (int j = 0; j < 4; ++j) {
                int col = tx * 4 + j;
                Ss[row][col] = p[j] * ((pr == (col >> 3)) ? 1.0f : sw);
            }
        }
        __syncthreads();           // Ss complete, K reads done
        #pragma unroll
        for (int i = 0; i < 16; ++i) {
            int e = tid + 256 * i;
            int r = e >> 6, d = e & 63;
            KV[r][d] = vbase[(size_t)(s0 + r) * D + d];
        }
        __syncthreads();
        // acc += P @ V
        #pragma unroll 8
        for (int sIdx = 0; sIdx < 64; ++sIdx) {
            float a[4], bb[4];
            #pragma unroll
            for (int i = 0; i < 4; ++i) a[i] = Ss[ty * 4 + i][sIdx];
            #pragma unroll
            for (int j = 0; j < 4; ++j) bb[j] = KV[sIdx][tx * 4 + j];
            #pragma unroll
            for (int i = 0; i < 4; ++i)
                #pragma unroll
                for (int j = 0; j < 4; ++j)
                    acc[i][j] += a[i] * bb[j];
        }
    }
    // epilogue
    #pragma unroll
    for (int i = 0; i < 4; ++i) {
        int row = t0 + ty * 4 + i;
        float inv = 1.0f / lrow[i];
        float4 o;
        o.x = acc[i][0] * inv;
        o.y = acc[i][1] * inv;
        o.z = acc[i][2] * inv;
        o.w = acc[i][3] * inv;
        *(float4*)(ao + (size_t)(b * T + row) * D + h * 64 + tx * 4) = o;
    }
}

// ---- GAT src/dst coefficients: one block per row --------------------------
__global__ __launch_bounds__(256) void gat_coeff_kernel(
    const float* __restrict__ hw, const float* __restrict__ a_src,
    const float* __restrict__ a_dst, float* __restrict__ sc,
    float* __restrict__ tc, int D)
{
    __shared__ float sbuf[4];
    int row = blockIdx.x;
    const float* hr = hw + (size_t)row * D;
    float s1 = 0.f, s2 = 0.f;
    for (int i = threadIdx.x; i < D; i += 256) {
        float h = hr[i];
        s1 += h * a_src[i];
        s2 += h * a_dst[i];
    }
    float t1 = block_reduce_sum(s1, sbuf);
    float t2 = block_reduce_sum(s2, sbuf);
    if (threadIdx.x == 0) { sc[row] = t1; tc[row] = t2; }
}

// ---- GAT aggregate, tiled: grid (D/64, T/64, B) ---------------------------
// h_gat[t,d] = (1/Z_t) sum_s exp(leaky(sc_t+tc_s) - M_t) * hw[s,d]
// M_t = leaky(sc_t + max_s tc_s)  (LeakyReLU monotone). Z accumulated in-reg.
__global__ __launch_bounds__(256) void gat_agg_tiled(
    const float* __restrict__ hw, const float* __restrict__ sc,
    const float* __restrict__ tc, float* __restrict__ hg, int T, int D)
{
    __shared__ float tcs[1024];
    __shared__ float Ws[64][65];
    __shared__ float Hs[64][65];
    __shared__ float wmax[4];

    int d0 = blockIdx.x * 64;
    int t0 = blockIdx.y * 64;
    int b = blockIdx.z;
    int tid = threadIdx.x;
    int tx = tid & 15, ty = tid >> 4;

    for (int i = tid; i < T; i += 256) tcs[i] = tc[b * T + i];
    __syncthreads();
    float lm = -1e30f;
    for (int i = tid; i < T; i += 256) lm = fmaxf(lm, tcs[i]);
    for (int off = 32; off; off >>= 1) lm = fmaxf(lm, __shfl_down(lm, off));
    if ((tid & 63) == 0) wmax[tid >> 6] = lm;
    __syncthreads();
    float tmax = fmaxf(fmaxf(wmax[0], wmax[1]), fmaxf(wmax[2], wmax[3]));

    float scr[4], M[4], z[4] = {0.f, 0.f, 0.f, 0.f};
    #pragma unroll
    for (int i = 0; i < 4; ++i) {
        float s = sc[b * T + t0 + ty * 4 + i];
        scr[i] = s;
        float e = s + tmax;
        M[i] = e > 0.f ? e : 0.2f * e;
    }
    float acc[4][4] = {{0.f}};

    for (int s0 = 0; s0 < T; s0 += 64) {
        __syncthreads();
        // W tile from sc/tc
        #pragma unroll
        for (int i = 0; i < 4; ++i) {
            #pragma unroll
            for (int j = 0; j < 4; ++j) {
                float e = scr[i] + tcs[s0 + tx * 4 + j];
                e = e > 0.f ? e : 0.2f * e;
                float p = __expf(e - M[i]);
                Ws[ty * 4 + i][tx * 4 + j] = p;
                z[i] += p;
            }
        }
        // H tile
        #pragma unroll
        for (int i = 0; i < 16; ++i) {
            int e = tid + 256 * i;
            int r = e >> 6, d = e & 63;
            Hs[r][d] = hw[(size_t)(b * T + s0 + r) * D + d0 + d];
        }
        __syncthreads();
        #pragma unroll 8
        for (int s = 0; s < 64; ++s) {
            float a[4], bb[4];
            #pragma unroll
            for (int i = 0; i < 4; ++i) a[i] = Ws[ty * 4 + i][s];
            #pragma unroll
            for (int j = 0; j < 4; ++j) bb[j] = Hs[s][tx * 4 + j];
            #pragma unroll
            for (int i = 0; i < 4; ++i)
                #pragma unroll
                for (int j = 0; j < 4; ++j)
                    acc[i][j] += a[i] * bb[j];
        }
    }
    #pragma unroll
    for (int i = 0; i < 4; ++i) {
        z[i] += __shfl_xor(z[i], 1);
        z[i] += __shfl_xor(z[i], 2);
        z[i] += __shfl_xor(z[i], 4);
        z[i] += __shfl_xor(z[i], 8);
        float inv = 1.0f / z[i];
        float4 o;
        o.x = acc[i][0] * inv;
        o.y = acc[i][1] * inv;
        o.z = acc[i][2] * inv;
        o.w = acc[i][3] * inv;
        *(float4*)(hg + (size_t)(b * T + t0 + ty * 4 + i) * D + d0 + tx * 4) = o;
    }
}

// ---- gated fusion: x2 = x + a*hp + (1-a)*hg -------------------------------
__global__ __launch_bounds__(256) void fuse_kernel(
    const float4* __restrict__ x, const float4* __restrict__ hp,
    const float4* __restrict__ hg, const float* __restrict__ gate,
    float4* __restrict__ x2, int n4)
{
    int i = blockIdx.x * 256 + threadIdx.x;
    if (i >= n4) return;
    float a = 1.0f / (1.0f + __expf(-gate[0]));
    float one_m = 1.0f - a;
    float4 xv = x[i], pv = hp[i], gv = hg[i];
    float4 o;
    o.x = xv.x + a * pv.x + one_m * gv.x;
    o.y = xv.y + a * pv.y + one_m * gv.y;
    o.z = xv.z + a * pv.z + one_m * gv.z;
    o.w = xv.w + a * pv.w + one_m * gv.w;
    x2[i] = o;
}

// ---------------------------------------------------------------------------
extern "C" void kernel_launch(void* const* d_in, const int* in_sizes, int n_in,
                              void* d_out, int out_size, void* d_ws, size_t ws_size,
                              hipStream_t stream) {
    const float* x      = (const float*)d_in[0];
    const float* Wq     = (const float*)d_in[1];
    const float* bq     = (const float*)d_in[2];
    const float* Wk     = (const float*)d_in[3];
    const float* bk     = (const float*)d_in[4];
    const float* Wv     = (const float*)d_in[5];
    const float* bv     = (const float*)d_in[6];
    const float* Wo     = (const float*)d_in[7];
    const float* bo     = (const float*)d_in[8];
    const float* interw = (const float*)d_in[9];
    const float* Wg     = (const float*)d_in[10];
    const float* a_src  = (const float*)d_in[11];
    const float* a_dst  = (const float*)d_in[12];
    const float* g1     = (const float*)d_in[13];
    const float* b1     = (const float*)d_in[14];
    const float* g2     = (const float*)d_in[15];
    const float* b2     = (const float*)d_in[16];
    const float* g3     = (const float*)d_in[17];
    const float* b3     = (const float*)d_in[18];
    const float* gate   = (const float*)d_in[19];
    const float* W1     = (const float*)d_in[20];
    const float* bf1    = (const float*)d_in[21];
    const float* W2     = (const float*)d_in[22];
    const float* bf2    = (const float*)d_in[23];

    const int D   = in_sizes[2];           // 1024
    const int BT  = in_sizes[0] / D;       // 2048
    const int T   = 1024;
    const int B   = BT / T;                // 2
    const int H   = 16;
    const int Dff = in_sizes[21];          // 4096

    float* ws = (float*)d_ws;
    const size_t SL = (size_t)BT * D;      // 2M floats per slot
    float* h1  = ws + 0 * SL;
    float* h2  = ws + 1 * SL;
    float* qb  = ws + 2 * SL;
    float* kb  = ws + 3 * SL;
    float* vb  = ws + 4 * SL;
    float* ao  = ws + 5 * SL;
    float* hp  = ws + 2 * SL;              // overwrites q (dead after attn)
    float* hw  = ws + 3 * SL;              // overwrites k
    float* hg  = ws + 4 * SL;              // overwrites v
    float* x2  = ws + 0 * SL;              // overwrites h1
    float* hf  = ws + 1 * SL;              // overwrites h2
    float* mid = ws + 2 * SL;              // spans slots 2..5 (BT*Dff floats)
    float* scb = ws + 6 * SL;
    float* tcb = scb + BT;

    dim3 blk(256);
    dim3 gD(D / TN, BT / TM);
    dim3 gF(Dff / TN, BT / TM);

    // LN branches
    ln_kernel<<<BT, blk, 0, stream>>>(x, g1, b1, h1, D);
    ln_kernel<<<BT, blk, 0, stream>>>(x, g2, b2, h2, D);

    // QKV projections
    gemm_kernel<<<gD, blk, 0, stream>>>(h1, Wq, bq, nullptr, qb, BT, D, D, 0);
    gemm_kernel<<<gD, blk, 0, stream>>>(h1, Wk, bk, nullptr, kb, BT, D, D, 0);
    gemm_kernel<<<gD, blk, 0, stream>>>(h1, Wv, bv, nullptr, vb, BT, D, D, 0);

    // palace attention (flash-style)
    attn_flash_kernel<<<dim3(T / 64, H, B), blk, 0, stream>>>(qb, kb, vb, interw, ao, T, H);
    gemm_kernel<<<gD, blk, 0, stream>>>(ao, Wo, bo, nullptr, hp, BT, D, D, 0);

    // GAT branch
    gemm_kernel<<<gD, blk, 0, stream>>>(h2, Wg, nullptr, nullptr, hw, BT, D, D, 0);
    gat_coeff_kernel<<<BT, blk, 0, stream>>>(hw, a_src, a_dst, scb, tcb, D);
    gat_agg_tiled<<<dim3(D / 64, T / 64, B), blk, 0, stream>>>(hw, scb, tcb, hg, T, D);

    // gated fusion + FFN
    int n4 = (int)(SL >> 2);
    fuse_kernel<<<(n4 + 255) / 256, blk, 0, stream>>>(
        (const float4*)x, (const float4*)hp, (const float4*)hg, gate, (float4*)x2, n4);
    ln_kernel<<<BT, blk, 0, stream>>>(x2, g3, b3, hf, D);
    gemm_kernel<<<gF, blk, 0, stream>>>(hf, W1, bf1, nullptr, mid, BT, Dff, D, 1);
    gemm_kernel<<<gD, blk, 0, stream>>>(mid, W2, bf2, x2, (float*)d_out, BT, D, Dff, 0);
}

// Round 3
// 591.316 us; speedup vs baseline: 9.1308x; 2.8884x over previous
//
#include <hip/hip_runtime.h>
#include <hip/hip_bf16.h>
#include <math.h>

// ---------------------------------------------------------------------------
// PalaceYiJingBlock — round 2: bf16 MFMA GEMMs (fp32 in/out), flash attention
// + tiled GAT unchanged. B=2, T=1024, D=1024, H=16, dh=64, Dff=4096.
// ---------------------------------------------------------------------------

typedef __attribute__((ext_vector_type(8))) __bf16 bf16x8_t;
typedef __attribute__((ext_vector_type(4))) float f32x4_t;

union PK2 { __bf16 h[4]; uint2 u; };
union PK4 { __bf16 h[8]; uint4 u; };

// ---- block-wide reduction (blockDim.x == 256) -----------------------------
__device__ __forceinline__ float block_reduce_sum(float v, float* sbuf) {
    for (int off = 32; off; off >>= 1) v += __shfl_down(v, off);
    int lane = threadIdx.x & 63, wid = threadIdx.x >> 6;
    if (lane == 0) sbuf[wid] = v;
    __syncthreads();
    float r = sbuf[0] + sbuf[1] + sbuf[2] + sbuf[3];
    __syncthreads();
    return r;
}

// ---- LayerNorm: one block per row -----------------------------------------
__global__ __launch_bounds__(256) void ln_kernel(
    const float* __restrict__ x, const float* __restrict__ g,
    const float* __restrict__ b, float* __restrict__ out, int D)
{
    __shared__ float sbuf[4];
    __shared__ float stats[2];
    int row = blockIdx.x;
    const float4* xr = (const float4*)(x + (size_t)row * D);
    float4* orow = (float4*)(out + (size_t)row * D);
    int tid = threadIdx.x;
    int n4 = D >> 2;
    float sum = 0.f, sumsq = 0.f;
    for (int i = tid; i < n4; i += 256) {
        float4 v = xr[i];
        sum += v.x + v.y + v.z + v.w;
        sumsq += v.x * v.x + v.y * v.y + v.z * v.z + v.w * v.w;
    }
    float ts = block_reduce_sum(sum, sbuf);
    float tq = block_reduce_sum(sumsq, sbuf);
    if (tid == 0) {
        float m = ts / (float)D;
        float var = tq / (float)D - m * m;
        stats[0] = m;
        stats[1] = rsqrtf(var + 1e-5f);
    }
    __syncthreads();
    float m = stats[0], r = stats[1];
    const float4* gv = (const float4*)g;
    const float4* bv = (const float4*)b;
    for (int i = tid; i < n4; i += 256) {
        float4 v = xr[i];
        float4 gg = gv[i];
        float4 bb = bv[i];
        float4 o;
        o.x = (v.x - m) * r * gg.x + bb.x;
        o.y = (v.y - m) * r * gg.y + bb.y;
        o.z = (v.z - m) * r * gg.z + bb.z;
        o.w = (v.w - m) * r * gg.w + bb.w;
        orow[i] = o;
    }
}

// ---- bf16 MFMA GEMM: C = act(A@W + bias) + resid --------------------------
// A [M,K] fp32, W [K,N] fp32 (converted to bf16 while staging; W transposed
// into LDS). BM=128, BN=64, BK=32; 256 threads = 4 waves in 2x2; each wave
// computes 64x32 via 4x2 fragments of mfma_f32_16x16x32_bf16.
// LDS rows padded to 40 bf16 (80 B): bank-base period 8 -> conflict-free
// ds_read_b128 fragment reads. Double-buffered, issue-early/write-late.
#define GBM 128
#define GBN 64
#define GBK 32
__global__ __launch_bounds__(256) void gemm_mfma(
    const float* __restrict__ A, const float* __restrict__ W,
    const float* __restrict__ bias, const float* __restrict__ resid,
    float* __restrict__ C, int M, int N, int K, int act)
{
    __shared__ __bf16 Al[2][GBM * 40];
    __shared__ __bf16 Bl[2][GBN * 40];

    int tid = threadIdx.x;
    int bm = blockIdx.y * GBM;
    int bn = blockIdx.x * GBN;

    // staging indices
    int ar0 = tid >> 3;        // 0..31 (A row base, +32 per pass)
    int ac4 = tid & 7;         // A col quad (4 floats)
    int bn_i = tid & 63;       // B: n within tile
    int bkh = tid >> 6;        // B: k-octet 0..3

    // wave/fragment indices
    int w = tid >> 6;
    int wr = w >> 1, wc = w & 1;
    int lane = tid & 63;
    int fr = lane & 15;        // fragment row/col
    int fs = lane >> 4;        // k-slice (8 elems)

    const int nt = K / GBK;

    float4 aR[4];
    float  bR[8];

    // ---- load tile 0 ----
    {
        const float* Ab = A + (size_t)bm * K;
        #pragma unroll
        for (int p = 0; p < 4; ++p)
            aR[p] = *(const float4*)&Ab[(size_t)(ar0 + 32 * p) * K + ac4 * 4];
        const float* Wb = W + (size_t)0 * N + bn;
        #pragma unroll
        for (int i = 0; i < 8; ++i)
            bR[i] = Wb[(size_t)(bkh * 8 + i) * N + bn_i];
    }
    // ---- write tile 0 ----
    {
        #pragma unroll
        for (int p = 0; p < 4; ++p) {
            PK2 pk;
            pk.h[0] = (__bf16)aR[p].x; pk.h[1] = (__bf16)aR[p].y;
            pk.h[2] = (__bf16)aR[p].z; pk.h[3] = (__bf16)aR[p].w;
            *(uint2*)&Al[0][(ar0 + 32 * p) * 40 + ac4 * 4] = pk.u;
        }
        PK4 pk;
        #pragma unroll
        for (int i = 0; i < 8; ++i) pk.h[i] = (__bf16)bR[i];
        *(uint4*)&Bl[0][bn_i * 40 + bkh * 8] = pk.u;
    }
    __syncthreads();

    f32x4_t acc[4][2];
    #pragma unroll
    for (int m = 0; m < 4; ++m)
        #pragma unroll
        for (int n = 0; n < 2; ++n)
            acc[m][n] = (f32x4_t){0.f, 0.f, 0.f, 0.f};

    for (int t = 0; t < nt; ++t) {
        int cur = t & 1;
        // issue next-tile global loads early (latency hidden by MFMAs)
        if (t + 1 < nt) {
            int k0 = (t + 1) * GBK;
            const float* Ab = A + (size_t)bm * K + k0;
            #pragma unroll
            for (int p = 0; p < 4; ++p)
                aR[p] = *(const float4*)&Ab[(size_t)(ar0 + 32 * p) * K + ac4 * 4];
            const float* Wb = W + (size_t)k0 * N + bn;
            #pragma unroll
            for (int i = 0; i < 8; ++i)
                bR[i] = Wb[(size_t)(bkh * 8 + i) * N + bn_i];
        }
        // compute from current buffer
        bf16x8_t af[4], bf[2];
        #pragma unroll
        for (int m = 0; m < 4; ++m)
            af[m] = *(bf16x8_t*)&Al[cur][(wr * 64 + m * 16 + fr) * 40 + fs * 8];
        #pragma unroll
        for (int n = 0; n < 2; ++n)
            bf[n] = *(bf16x8_t*)&Bl[cur][(wc * 32 + n * 16 + fr) * 40 + fs * 8];
        #pragma unroll
        for (int m = 0; m < 4; ++m)
            #pragma unroll
            for (int n = 0; n < 2; ++n)
                acc[m][n] = __builtin_amdgcn_mfma_f32_16x16x32_bf16(
                    af[m], bf[n], acc[m][n], 0, 0, 0);
        // write next tile into the other buffer
        if (t + 1 < nt) {
            int nxt = cur ^ 1;
            #pragma unroll
            for (int p = 0; p < 4; ++p) {
                PK2 pk;
                pk.h[0] = (__bf16)aR[p].x; pk.h[1] = (__bf16)aR[p].y;
                pk.h[2] = (__bf16)aR[p].z; pk.h[3] = (__bf16)aR[p].w;
                *(uint2*)&Al[nxt][(ar0 + 32 * p) * 40 + ac4 * 4] = pk.u;
            }
            PK4 pk;
            #pragma unroll
            for (int i = 0; i < 8; ++i) pk.h[i] = (__bf16)bR[i];
            *(uint4*)&Bl[nxt][bn_i * 40 + bkh * 8] = pk.u;
        }
        __syncthreads();
    }

    // ---- epilogue: bias / GELU / residual, fp32 store ----
    #pragma unroll
    for (int m = 0; m < 4; ++m) {
        #pragma unroll
        for (int n = 0; n < 2; ++n) {
            int col = bn + wc * 32 + n * 16 + fr;
            float bv = bias ? bias[col] : 0.f;
            #pragma unroll
            for (int r = 0; r < 4; ++r) {
                int row = bm + wr * 64 + m * 16 + fs * 4 + r;
                float val = acc[m][n][r] + bv;
                if (act == 1) val = 0.5f * val * (1.0f + erff(val * 0.70710678118654752f));
                if (resid) val += resid[(size_t)row * N + col];
                C[(size_t)row * N + col] = val;
            }
        }
    }
}

// ---- flash-style palace attention -----------------------------------------
__global__ __launch_bounds__(256) void attn_flash_kernel(
    const float* __restrict__ q, const float* __restrict__ k,
    const float* __restrict__ v, const float* __restrict__ inter_w,
    float* __restrict__ ao, int T, int H)
{
    __shared__ float Qs[64][65];
    __shared__ float KV[64][65];
    __shared__ float Ss[64][65];

    int t0 = blockIdx.x * 64;
    int h = blockIdx.y, b = blockIdx.z;
    int D = H * 64;
    int tid = threadIdx.x;
    int tx = tid & 15, ty = tid >> 4;
    float sw = 1.0f / (1.0f + __expf(-inter_w[0]));

    const float* qbase = q + (size_t)(b * T + t0) * D + h * 64;
    const float* kbase = k + (size_t)(b * T) * D + h * 64;
    const float* vbase = v + (size_t)(b * T) * D + h * 64;

    #pragma unroll
    for (int i = 0; i < 16; ++i) {
        int e = tid + 256 * i;
        int r = e >> 6, d = e & 63;
        Qs[r][d] = qbase[(size_t)r * D + d] * 0.125f;
    }

    float acc[4][4] = {{0.f}};
    float mrow[4] = {-1e30f, -1e30f, -1e30f, -1e30f};
    float lrow[4] = {0.f, 0.f, 0.f, 0.f};

    for (int s0 = 0; s0 < T; s0 += 64) {
        __syncthreads();
        #pragma unroll
        for (int i = 0; i < 16; ++i) {
            int e = tid + 256 * i;
            int r = e >> 6, d = e & 63;
            KV[r][d] = kbase[(size_t)(s0 + r) * D + d];
        }
        __syncthreads();
        float s[4][4] = {{0.f}};
        #pragma unroll 8
        for (int d = 0; d < 64; ++d) {
            float a[4], bb[4];
            #pragma unroll
            for (int i = 0; i < 4; ++i) a[i] = Qs[ty * 4 + i][d];
            #pragma unroll
            for (int j = 0; j < 4; ++j) bb[j] = KV[tx * 4 + j][d];
            #pragma unroll
            for (int i = 0; i < 4; ++i)
                #pragma unroll
                for (int j = 0; j < 4; ++j)
                    s[i][j] += a[i] * bb[j];
        }
        #pragma unroll
        for (int i = 0; i < 4; ++i) {
            int row = ty * 4 + i;
            float rm = fmaxf(fmaxf(s[i][0], s[i][1]), fmaxf(s[i][2], s[i][3]));
            rm = fmaxf(rm, __shfl_xor(rm, 1));
            rm = fmaxf(rm, __shfl_xor(rm, 2));
            rm = fmaxf(rm, __shfl_xor(rm, 4));
            rm = fmaxf(rm, __shfl_xor(rm, 8));
            float mnew = fmaxf(mrow[i], rm);
            float resc = __expf(mrow[i] - mnew);
            mrow[i] = mnew;
            #pragma unroll
            for (int j = 0; j < 4; ++j) acc[i][j] *= resc;
            float rs = 0.f;
            float p[4];
            #pragma unroll
            for (int j = 0; j < 4; ++j) {
                p[j] = __expf(s[i][j] - mnew);
                rs += p[j];
            }
            rs += __shfl_xor(rs, 1);
            rs += __shfl_xor(rs, 2);
            rs += __shfl_xor(rs, 4);
            rs += __shfl_xor(rs, 8);
            lrow[i] = lrow[i] * resc + rs;
            int pr = row >> 3;
            #pragma unroll
            for (int j = 0; j < 4; ++j) {
                int col = tx * 4 + j;
                Ss[row][col] = p[j] * ((pr == (col >> 3)) ? 1.0f : sw);
            }
        }
        __syncthreads();
        #pragma unroll
        for (int i = 0; i < 16; ++i) {
            int e = tid + 256 * i;
            int r = e >> 6, d = e & 63;
            KV[r][d] = vbase[(size_t)(s0 + r) * D + d];
        }
        __syncthreads();
        #pragma unroll 8
        for (int sIdx = 0; sIdx < 64; ++sIdx) {
            float a[4], bb[4];
            #pragma unroll
            for (int i = 0; i < 4; ++i) a[i] = Ss[ty * 4 + i][sIdx];
            #pragma unroll
            for (int j = 0; j < 4; ++j) bb[j] = KV[sIdx][tx * 4 + j];
            #pragma unroll
            for (int i = 0; i < 4; ++i)
                #pragma unroll
                for (int j = 0; j < 4; ++j)
                    acc[i][j] += a[i] * bb[j];
        }
    }
    #pragma unroll
    for (int i = 0; i < 4; ++i) {
        int row = t0 + ty * 4 + i;
        float inv = 1.0f / lrow[i];
        float4 o;
        o.x = acc[i][0] * inv;
        o.y = acc[i][1] * inv;
        o.z = acc[i][2] * inv;
        o.w = acc[i][3] * inv;
        *(float4*)(ao + (size_t)(b * T + row) * D + h * 64 + tx * 4) = o;
    }
}

// ---- GAT src/dst coefficients: one block per row --------------------------
__global__ __launch_bounds__(256) void gat_coeff_kernel(
    const float* __restrict__ hw, const float* __restrict__ a_src,
    const float* __restrict__ a_dst, float* __restrict__ sc,
    float* __restrict__ tc, int D)
{
    __shared__ float sbuf[4];
    int row = blockIdx.x;
    const float* hr = hw + (size_t)row * D;
    float s1 = 0.f, s2 = 0.f;
    for (int i = threadIdx.x; i < D; i += 256) {
        float h = hr[i];
        s1 += h * a_src[i];
        s2 += h * a_dst[i];
    }
    float t1 = block_reduce_sum(s1, sbuf);
    float t2 = block_reduce_sum(s2, sbuf);
    if (threadIdx.x == 0) { sc[row] = t1; tc[row] = t2; }
}

// ---- GAT aggregate, tiled: grid (D/64, T/64, B) ---------------------------
__global__ __launch_bounds__(256) void gat_agg_tiled(
    const float* __restrict__ hw, const float* __restrict__ sc,
    const float* __restrict__ tc, float* __restrict__ hg, int T, int D)
{
    __shared__ float tcs[1024];
    __shared__ float Ws[64][65];
    __shared__ float Hs[64][65];
    __shared__ float wmax[4];

    int d0 = blockIdx.x * 64;
    int t0 = blockIdx.y * 64;
    int b = blockIdx.z;
    int tid = threadIdx.x;
    int tx = tid & 15, ty = tid >> 4;

    for (int i = tid; i < T; i += 256) tcs[i] = tc[b * T + i];
    __syncthreads();
    float lm = -1e30f;
    for (int i = tid; i < T; i += 256) lm = fmaxf(lm, tcs[i]);
    for (int off = 32; off; off >>= 1) lm = fmaxf(lm, __shfl_down(lm, off));
    if ((tid & 63) == 0) wmax[tid >> 6] = lm;
    __syncthreads();
    float tmax = fmaxf(fmaxf(wmax[0], wmax[1]), fmaxf(wmax[2], wmax[3]));

    float scr[4], M[4], z[4] = {0.f, 0.f, 0.f, 0.f};
    #pragma unroll
    for (int i = 0; i < 4; ++i) {
        float s = sc[b * T + t0 + ty * 4 + i];
        scr[i] = s;
        float e = s + tmax;
        M[i] = e > 0.f ? e : 0.2f * e;
    }
    float acc[4][4] = {{0.f}};

    for (int s0 = 0; s0 < T; s0 += 64) {
        __syncthreads();
        #pragma unroll
        for (int i = 0; i < 4; ++i) {
            #pragma unroll
            for (int j = 0; j < 4; ++j) {
                float e = scr[i] + tcs[s0 + tx * 4 + j];
                e = e > 0.f ? e : 0.2f * e;
                float p = __expf(e - M[i]);
                Ws[ty * 4 + i][tx * 4 + j] = p;
                z[i] += p;
            }
        }
        #pragma unroll
        for (int i = 0; i < 16; ++i) {
            int e = tid + 256 * i;
            int r = e >> 6, d = e & 63;
            Hs[r][d] = hw[(size_t)(b * T + s0 + r) * D + d0 + d];
        }
        __syncthreads();
        #pragma unroll 8
        for (int s = 0; s < 64; ++s) {
            float a[4], bb[4];
            #pragma unroll
            for (int i = 0; i < 4; ++i) a[i] = Ws[ty * 4 + i][s];
            #pragma unroll
            for (int j = 0; j < 4; ++j) bb[j] = Hs[s][tx * 4 + j];
            #pragma unroll
            for (int i = 0; i < 4; ++i)
                #pragma unroll
                for (int j = 0; j < 4; ++j)
                    acc[i][j] += a[i] * bb[j];
        }
    }
    #pragma unroll
    for (int i = 0; i < 4; ++i) {
        z[i] += __shfl_xor(z[i], 1);
        z[i] += __shfl_xor(z[i], 2);
        z[i] += __shfl_xor(z[i], 4);
        z[i] += __shfl_xor(z[i], 8);
        float inv = 1.0f / z[i];
        float4 o;
        o.x = acc[i][0] * inv;
        o.y = acc[i][1] * inv;
        o.z = acc[i][2] * inv;
        o.w = acc[i][3] * inv;
        *(float4*)(hg + (size_t)(b * T + t0 + ty * 4 + i) * D + d0 + tx * 4) = o;
    }
}

// ---- gated fusion: x2 = x + a*hp + (1-a)*hg -------------------------------
__global__ __launch_bounds__(256) void fuse_kernel(
    const float4* __restrict__ x, const float4* __restrict__ hp,
    const float4* __restrict__ hg, const float* __restrict__ gate,
    float4* __restrict__ x2, int n4)
{
    int i = blockIdx.x * 256 + threadIdx.x;
    if (i >= n4) return;
    float a = 1.0f / (1.0f + __expf(-gate[0]));
    float one_m = 1.0f - a;
    float4 xv = x[i], pv = hp[i], gv = hg[i];
    float4 o;
    o.x = xv.x + a * pv.x + one_m * gv.x;
    o.y = xv.y + a * pv.y + one_m * gv.y;
    o.z = xv.z + a * pv.z + one_m * gv.z;
    o.w = xv.w + a * pv.w + one_m * gv.w;
    x2[i] = o;
}

// ---------------------------------------------------------------------------
extern "C" void kernel_launch(void* const* d_in, const int* in_sizes, int n_in,
                              void* d_out, int out_size, void* d_ws, size_t ws_size,
                              hipStream_t stream) {
    const float* x      = (const float*)d_in[0];
    const float* Wq     = (const float*)d_in[1];
    const float* bq     = (const float*)d_in[2];
    const float* Wk     = (const float*)d_in[3];
    const float* bk     = (const float*)d_in[4];
    const float* Wv     = (const float*)d_in[5];
    const float* bv     = (const float*)d_in[6];
    const float* Wo     = (const float*)d_in[7];
    const float* bo     = (const float*)d_in[8];
    const float* interw = (const float*)d_in[9];
    const float* Wg     = (const float*)d_in[10];
    const float* a_src  = (const float*)d_in[11];
    const float* a_dst  = (const float*)d_in[12];
    const float* g1     = (const float*)d_in[13];
    const float* b1     = (const float*)d_in[14];
    const float* g2     = (const float*)d_in[15];
    const float* b2     = (const float*)d_in[16];
    const float* g3     = (const float*)d_in[17];
    const float* b3     = (const float*)d_in[18];
    const float* gate   = (const float*)d_in[19];
    const float* W1     = (const float*)d_in[20];
    const float* bf1    = (const float*)d_in[21];
    const float* W2     = (const float*)d_in[22];
    const float* bf2    = (const float*)d_in[23];

    const int D   = in_sizes[2];           // 1024
    const int BT  = in_sizes[0] / D;       // 2048
    const int T   = 1024;
    const int B   = BT / T;                // 2
    const int H   = 16;
    const int Dff = in_sizes[21];          // 4096

    float* ws = (float*)d_ws;
    const size_t SL = (size_t)BT * D;      // 2M floats per slot
    float* h1  = ws + 0 * SL;
    float* h2  = ws + 1 * SL;
    float* qb  = ws + 2 * SL;
    float* kb  = ws + 3 * SL;
    float* vb  = ws + 4 * SL;
    float* ao  = ws + 5 * SL;
    float* hp  = ws + 2 * SL;              // overwrites q (dead after attn)
    float* hw  = ws + 3 * SL;              // overwrites k
    float* hg  = ws + 4 * SL;              // overwrites v
    float* x2  = ws + 0 * SL;              // overwrites h1
    float* hf  = ws + 1 * SL;              // overwrites h2
    float* mid = ws + 2 * SL;              // spans slots 2..5 (BT*Dff floats)
    float* scb = ws + 6 * SL;
    float* tcb = scb + BT;

    dim3 blk(256);
    dim3 gD(D / GBN, BT / GBM);            // (16,16)
    dim3 gF(Dff / GBN, BT / GBM);          // (64,16)

    // LN branches
    ln_kernel<<<BT, blk, 0, stream>>>(x, g1, b1, h1, D);
    ln_kernel<<<BT, blk, 0, stream>>>(x, g2, b2, h2, D);

    // QKV projections (bf16 MFMA)
    gemm_mfma<<<gD, blk, 0, stream>>>(h1, Wq, bq, nullptr, qb, BT, D, D, 0);
    gemm_mfma<<<gD, blk, 0, stream>>>(h1, Wk, bk, nullptr, kb, BT, D, D, 0);
    gemm_mfma<<<gD, blk, 0, stream>>>(h1, Wv, bv, nullptr, vb, BT, D, D, 0);

    // palace attention (flash-style)
    attn_flash_kernel<<<dim3(T / 64, H, B), blk, 0, stream>>>(qb, kb, vb, interw, ao, T, H);
    gemm_mfma<<<gD, blk, 0, stream>>>(ao, Wo, bo, nullptr, hp, BT, D, D, 0);

    // GAT branch
    gemm_mfma<<<gD, blk, 0, stream>>>(h2, Wg, nullptr, nullptr, hw, BT, D, D, 0);
    gat_coeff_kernel<<<BT, blk, 0, stream>>>(hw, a_src, a_dst, scb, tcb, D);
    gat_agg_tiled<<<dim3(D / 64, T / 64, B), blk, 0, stream>>>(hw, scb, tcb, hg, T, D);

    // gated fusion + FFN
    int n4 = (int)(SL >> 2);
    fuse_kernel<<<(n4 + 255) / 256, blk, 0, stream>>>(
        (const float4*)x, (const float4*)hp, (const float4*)hg, gate, (float4*)x2, n4);
    ln_kernel<<<BT, blk, 0, stream>>>(x2, g3, b3, hf, D);
    gemm_mfma<<<gF, blk, 0, stream>>>(hf, W1, bf1, nullptr, mid, BT, Dff, D, 1);
    gemm_mfma<<<gD, blk, 0, stream>>>(mid, W2, bf2, x2, (float*)d_out, BT, D, Dff, 0);
}

// Round 4
// 386.771 us; speedup vs baseline: 13.9597x; 1.5289x over previous
//
#include <hip/hip_runtime.h>
#include <hip/hip_bf16.h>
#include <math.h>

// ---------------------------------------------------------------------------
// PalaceYiJingBlock — round 3: MFMA attention + MFMA GAT + bf16 intermediates.
// B=2, T=1024, D=1024, H=16, dh=64, Dff=4096.
// ---------------------------------------------------------------------------

typedef __attribute__((ext_vector_type(8))) __bf16 bf16x8_t;
typedef __attribute__((ext_vector_type(4))) float f32x4_t;

union PK2 { __bf16 h[4]; uint2 u; };
union PK4 { __bf16 h[8]; uint4 u; unsigned w[4]; bf16x8_t v; };

// swizzled LDS addressing for 64-col bf16 tiles (row stride 64 elems = 128 B):
// chunk c (8 elems) lives at c ^ (row&7)  -> conflict-free b128 frag reads.
__device__ __forceinline__ int swz16(int row, int c) {
    return row * 64 + ((c ^ (row & 7)) << 3);
}
__device__ __forceinline__ int swzel(int row, int col) {
    return row * 64 + ((((col >> 3) ^ (row & 7))) << 3) + (col & 7);
}

// ---- block-wide reduction (blockDim.x == 256) -----------------------------
__device__ __forceinline__ float block_reduce_sum(float v, float* sbuf) {
    for (int off = 32; off; off >>= 1) v += __shfl_down(v, off);
    int lane = threadIdx.x & 63, wid = threadIdx.x >> 6;
    if (lane == 0) sbuf[wid] = v;
    __syncthreads();
    float r = sbuf[0] + sbuf[1] + sbuf[2] + sbuf[3];
    __syncthreads();
    return r;
}

// ---- LayerNorm: one block per row -----------------------------------------
__global__ __launch_bounds__(256) void ln_kernel(
    const float* __restrict__ x, const float* __restrict__ g,
    const float* __restrict__ b, float* __restrict__ out, int D)
{
    __shared__ float sbuf[4];
    __shared__ float stats[2];
    int row = blockIdx.x;
    const float4* xr = (const float4*)(x + (size_t)row * D);
    float4* orow = (float4*)(out + (size_t)row * D);
    int tid = threadIdx.x;
    int n4 = D >> 2;
    float sum = 0.f, sumsq = 0.f;
    for (int i = tid; i < n4; i += 256) {
        float4 v = xr[i];
        sum += v.x + v.y + v.z + v.w;
        sumsq += v.x * v.x + v.y * v.y + v.z * v.z + v.w * v.w;
    }
    float ts = block_reduce_sum(sum, sbuf);
    float tq = block_reduce_sum(sumsq, sbuf);
    if (tid == 0) {
        float m = ts / (float)D;
        float var = tq / (float)D - m * m;
        stats[0] = m;
        stats[1] = rsqrtf(var + 1e-5f);
    }
    __syncthreads();
    float m = stats[0], r = stats[1];
    const float4* gv = (const float4*)g;
    const float4* bv = (const float4*)b;
    for (int i = tid; i < n4; i += 256) {
        float4 v = xr[i];
        float4 gg = gv[i];
        float4 bb = bv[i];
        float4 o;
        o.x = (v.x - m) * r * gg.x + bb.x;
        o.y = (v.y - m) * r * gg.y + bb.y;
        o.z = (v.z - m) * r * gg.z + bb.z;
        o.w = (v.w - m) * r * gg.w + bb.w;
        orow[i] = o;
    }
}

// ---- bf16 MFMA GEMM -------------------------------------------------------
// A [M,K] (fp32 or bf16), W [K,N] fp32. BM=128,BN=64,BK=32; 4 waves (2x2);
// each wave 64x32 via 4x2 frags of mfma_f32_16x16x32_bf16. LDS rows padded
// to 40 bf16. Double-buffered, issue-early/write-late.
#define GBM 128
#define GBN 64
#define GBK 32
template<bool ABF16, bool CBF16, bool GELU>
__global__ __launch_bounds__(256) void gemm_mfma(
    const void* __restrict__ Ap, const float* __restrict__ W,
    const float* __restrict__ bias, const float* __restrict__ resid,
    void* __restrict__ Cp, int M, int N, int K)
{
    __shared__ __bf16 Al[2][GBM * 40];
    __shared__ __bf16 Bl[2][GBN * 40];

    const float* Af = (const float*)Ap;
    const __bf16* Ab = (const __bf16*)Ap;

    int tid = threadIdx.x;
    int bm = blockIdx.y * GBM;
    int bn = blockIdx.x * GBN;

    int ar0 = tid >> 3;        // fp32-A: row base
    int ac4 = tid & 7;         // fp32-A: col quad
    int bn_i = tid & 63;       // B: n
    int bkh = tid >> 6;        // B: k-octet

    int w = tid >> 6;
    int wr = w >> 1, wc = w & 1;
    int lane = tid & 63;
    int fr = lane & 15;
    int fs = lane >> 4;

    const int nt = K / GBK;

    float4 aR[4];
    uint4  aU[2];
    float  bR[8];

    auto loadA = [&](int k0) {
        if constexpr (ABF16) {
            #pragma unroll
            for (int p = 0; p < 2; ++p) {
                int e = tid + 256 * p; int r = e >> 2, c = e & 3;
                aU[p] = *(const uint4*)(Ab + (size_t)(bm + r) * K + k0 + c * 8);
            }
        } else {
            #pragma unroll
            for (int p = 0; p < 4; ++p)
                aR[p] = *(const float4*)(Af + (size_t)(bm + ar0 + 32 * p) * K + k0 + ac4 * 4);
        }
    };
    auto writeA = [&](int buf) {
        if constexpr (ABF16) {
            #pragma unroll
            for (int p = 0; p < 2; ++p) {
                int e = tid + 256 * p; int r = e >> 2, c = e & 3;
                *(uint4*)&Al[buf][r * 40 + c * 8] = aU[p];
            }
        } else {
            #pragma unroll
            for (int p = 0; p < 4; ++p) {
                PK2 pk;
                pk.h[0] = (__bf16)aR[p].x; pk.h[1] = (__bf16)aR[p].y;
                pk.h[2] = (__bf16)aR[p].z; pk.h[3] = (__bf16)aR[p].w;
                *(uint2*)&Al[buf][(ar0 + 32 * p) * 40 + ac4 * 4] = pk.u;
            }
        }
    };
    auto loadB = [&](int k0) {
        const float* Wb = W + (size_t)k0 * N + bn;
        #pragma unroll
        for (int i = 0; i < 8; ++i)
            bR[i] = Wb[(size_t)(bkh * 8 + i) * N + bn_i];
    };
    auto writeB = [&](int buf) {
        PK4 pk;
        #pragma unroll
        for (int i = 0; i < 8; ++i) pk.h[i] = (__bf16)bR[i];
        *(uint4*)&Bl[buf][bn_i * 40 + bkh * 8] = pk.u;
    };

    loadA(0); loadB(0);
    writeA(0); writeB(0);
    __syncthreads();

    f32x4_t acc[4][2];
    #pragma unroll
    for (int m = 0; m < 4; ++m)
        #pragma unroll
        for (int n = 0; n < 2; ++n)
            acc[m][n] = (f32x4_t){0.f, 0.f, 0.f, 0.f};

    for (int t = 0; t < nt; ++t) {
        int cur = t & 1;
        if (t + 1 < nt) { loadA((t + 1) * GBK); loadB((t + 1) * GBK); }
        bf16x8_t af[4], bf[2];
        #pragma unroll
        for (int m = 0; m < 4; ++m)
            af[m] = *(bf16x8_t*)&Al[cur][(wr * 64 + m * 16 + fr) * 40 + fs * 8];
        #pragma unroll
        for (int n = 0; n < 2; ++n)
            bf[n] = *(bf16x8_t*)&Bl[cur][(wc * 32 + n * 16 + fr) * 40 + fs * 8];
        #pragma unroll
        for (int m = 0; m < 4; ++m)
            #pragma unroll
            for (int n = 0; n < 2; ++n)
                acc[m][n] = __builtin_amdgcn_mfma_f32_16x16x32_bf16(
                    af[m], bf[n], acc[m][n], 0, 0, 0);
        if (t + 1 < nt) { writeA(cur ^ 1); writeB(cur ^ 1); }
        __syncthreads();
    }

    #pragma unroll
    for (int m = 0; m < 4; ++m) {
        #pragma unroll
        for (int n = 0; n < 2; ++n) {
            int col = bn + wc * 32 + n * 16 + fr;
            float bv = bias ? bias[col] : 0.f;
            #pragma unroll
            for (int r = 0; r < 4; ++r) {
                int row = bm + wr * 64 + m * 16 + fs * 4 + r;
                float val = acc[m][n][r] + bv;
                if constexpr (GELU)
                    val = 0.5f * val * (1.0f + erff(val * 0.70710678118654752f));
                if constexpr (CBF16) {
                    ((__bf16*)Cp)[(size_t)row * N + col] = (__bf16)val;
                } else {
                    if (resid) val += resid[(size_t)row * N + col];
                    ((float*)Cp)[(size_t)row * N + col] = val;
                }
            }
        }
    }
}

// ---- 64x64-tile bf16 transpose: in [b][t][D] -> out [b][d][T] -------------
__global__ __launch_bounds__(256) void transpose_bf16_64(
    const __bf16* __restrict__ in, __bf16* __restrict__ out, int T, int D)
{
    __shared__ __bf16 tile[64 * 66];
    int t0 = blockIdx.x * 64, d0 = blockIdx.y * 64, b = blockIdx.z;
    int tid = threadIdx.x;
    #pragma unroll
    for (int i = 0; i < 2; ++i) {
        int e = tid + 256 * i; int r = e >> 3, c = e & 7;
        PK4 pk;
        pk.u = *(const uint4*)(in + ((size_t)(b * T + t0 + r)) * D + d0 + c * 8);
        #pragma unroll
        for (int q = 0; q < 4; ++q)
            *(unsigned*)&tile[r * 66 + c * 8 + q * 2] = pk.w[q];
    }
    __syncthreads();
    #pragma unroll
    for (int i = 0; i < 2; ++i) {
        int e = tid + 256 * i; int dd = e >> 3, tch = e & 7;
        PK4 pk;
        #pragma unroll
        for (int j = 0; j < 8; ++j) pk.h[j] = tile[(tch * 8 + j) * 66 + dd];
        *(uint4*)(out + ((size_t)(b * D + d0 + dd)) * T + t0 + tch * 8) = pk.u;
    }
}

// ---- MFMA flash palace attention ------------------------------------------
// grid (T/64, H, B), 256 thr = 4 waves x 16 q-rows. K/V tiles 64. V consumed
// transposed (vt). Palace mask post-exp, excluded from denominator.
__global__ __launch_bounds__(256) void attn_mfma(
    const __bf16* __restrict__ qb, const __bf16* __restrict__ kb,
    const __bf16* __restrict__ vt, const float* __restrict__ inter_w,
    __bf16* __restrict__ ao, int T, int H)
{
    __shared__ __bf16 Qs[64 * 64];
    __shared__ __bf16 Ks[64 * 64];
    __shared__ __bf16 Vs[64 * 64];
    __shared__ __bf16 Ps[64 * 64];

    int t0 = blockIdx.x * 64, h = blockIdx.y, b = blockIdx.z;
    int D = H * 64;
    int tid = threadIdx.x;
    int w = tid >> 6, lane = tid & 63, fr = lane & 15, fs = lane >> 4;
    float sw = 1.0f / (1.0f + __expf(-inter_w[0]));
    float mm[4];
    int palr = w * 2 + (fs >> 1);
    #pragma unroll
    for (int n = 0; n < 4; ++n)
        mm[n] = (palr == n * 2 + (fr >> 3)) ? 1.0f : sw;

    const __bf16* qbase = qb + ((size_t)b * T + t0) * D + h * 64;
    const __bf16* kbase = kb + (size_t)b * T * D + h * 64;
    const __bf16* vbase = vt + ((size_t)b * D + h * 64) * T;

    #pragma unroll
    for (int i = 0; i < 2; ++i) {
        int e = tid + 256 * i; int r = e >> 3, c = e & 7;
        PK4 pk; pk.u = *(const uint4*)(qbase + (size_t)r * D + c * 8);
        #pragma unroll
        for (int j = 0; j < 8; ++j) pk.h[j] = (__bf16)((float)pk.h[j] * 0.125f);
        *(uint4*)&Qs[swz16(r, c)] = pk.u;
    }

    f32x4_t acc[4];
    #pragma unroll
    for (int d = 0; d < 4; ++d) acc[d] = (f32x4_t){0.f, 0.f, 0.f, 0.f};
    float mrow[4] = {-1e30f, -1e30f, -1e30f, -1e30f};
    float lrow[4] = {0.f, 0.f, 0.f, 0.f};

    for (int s0 = 0; s0 < T; s0 += 64) {
        __syncthreads();
        #pragma unroll
        for (int i = 0; i < 2; ++i) {
            int e = tid + 256 * i; int r = e >> 3, c = e & 7;
            *(uint4*)&Ks[swz16(r, c)] = *(const uint4*)(kbase + (size_t)(s0 + r) * D + c * 8);
            *(uint4*)&Vs[swz16(r, c)] = *(const uint4*)(vbase + (size_t)r * T + s0 + c * 8);
        }
        __syncthreads();
        bf16x8_t aq0 = *(bf16x8_t*)&Qs[swz16(w * 16 + fr, fs)];
        bf16x8_t aq1 = *(bf16x8_t*)&Qs[swz16(w * 16 + fr, 4 + fs)];
        f32x4_t s4[4];
        #pragma unroll
        for (int n = 0; n < 4; ++n) {
            bf16x8_t b0 = *(bf16x8_t*)&Ks[swz16(n * 16 + fr, fs)];
            bf16x8_t b1 = *(bf16x8_t*)&Ks[swz16(n * 16 + fr, 4 + fs)];
            f32x4_t z = (f32x4_t){0.f, 0.f, 0.f, 0.f};
            z = __builtin_amdgcn_mfma_f32_16x16x32_bf16(aq0, b0, z, 0, 0, 0);
            s4[n] = __builtin_amdgcn_mfma_f32_16x16x32_bf16(aq1, b1, z, 0, 0, 0);
        }
        #pragma unroll
        for (int r_ = 0; r_ < 4; ++r_) {
            float mx = fmaxf(fmaxf(s4[0][r_], s4[1][r_]), fmaxf(s4[2][r_], s4[3][r_]));
            mx = fmaxf(mx, __shfl_xor(mx, 1));
            mx = fmaxf(mx, __shfl_xor(mx, 2));
            mx = fmaxf(mx, __shfl_xor(mx, 4));
            mx = fmaxf(mx, __shfl_xor(mx, 8));
            float mnew = fmaxf(mrow[r_], mx);
            float resc = __expf(mrow[r_] - mnew);
            mrow[r_] = mnew;
            float p0 = __expf(s4[0][r_] - mnew);
            float p1 = __expf(s4[1][r_] - mnew);
            float p2 = __expf(s4[2][r_] - mnew);
            float p3 = __expf(s4[3][r_] - mnew);
            float rs = p0 + p1 + p2 + p3;
            rs += __shfl_xor(rs, 1);
            rs += __shfl_xor(rs, 2);
            rs += __shfl_xor(rs, 4);
            rs += __shfl_xor(rs, 8);
            lrow[r_] = lrow[r_] * resc + rs;
            acc[0][r_] *= resc; acc[1][r_] *= resc;
            acc[2][r_] *= resc; acc[3][r_] *= resc;
            int prow = w * 16 + fs * 4 + r_;
            Ps[swzel(prow,  0 + fr)] = (__bf16)(p0 * mm[0]);
            Ps[swzel(prow, 16 + fr)] = (__bf16)(p1 * mm[1]);
            Ps[swzel(prow, 32 + fr)] = (__bf16)(p2 * mm[2]);
            Ps[swzel(prow, 48 + fr)] = (__bf16)(p3 * mm[3]);
        }
        // P rows are wave-local: no barrier needed before re-reading own rows.
        bf16x8_t ap0 = *(bf16x8_t*)&Ps[swz16(w * 16 + fr, fs)];
        bf16x8_t ap1 = *(bf16x8_t*)&Ps[swz16(w * 16 + fr, 4 + fs)];
        #pragma unroll
        for (int d = 0; d < 4; ++d) {
            bf16x8_t b0 = *(bf16x8_t*)&Vs[swz16(d * 16 + fr, fs)];
            bf16x8_t b1 = *(bf16x8_t*)&Vs[swz16(d * 16 + fr, 4 + fs)];
            acc[d] = __builtin_amdgcn_mfma_f32_16x16x32_bf16(ap0, b0, acc[d], 0, 0, 0);
            acc[d] = __builtin_amdgcn_mfma_f32_16x16x32_bf16(ap1, b1, acc[d], 0, 0, 0);
        }
    }
    float inv[4];
    #pragma unroll
    for (int r_ = 0; r_ < 4; ++r_) inv[r_] = 1.0f / lrow[r_];
    #pragma unroll
    for (int d = 0; d < 4; ++d) {
        int col = h * 64 + d * 16 + fr;
        #pragma unroll
        for (int r_ = 0; r_ < 4; ++r_) {
            int row = t0 + w * 16 + fs * 4 + r_;
            ao[((size_t)b * T + row) * D + col] = (__bf16)(acc[d][r_] * inv[r_]);
        }
    }
}

// ---- GAT src/dst coefficients (bf16 input) --------------------------------
__global__ __launch_bounds__(256) void gat_coeff_kernel(
    const __bf16* __restrict__ hw, const float* __restrict__ a_src,
    const float* __restrict__ a_dst, float* __restrict__ sc,
    float* __restrict__ tc, int D)
{
    __shared__ float sbuf[4];
    int row = blockIdx.x;
    const __bf16* hr = hw + (size_t)row * D;
    float s1 = 0.f, s2 = 0.f;
    for (int i = threadIdx.x; i < D; i += 256) {
        float h = (float)hr[i];
        s1 += h * a_src[i];
        s2 += h * a_dst[i];
    }
    float t1 = block_reduce_sum(s1, sbuf);
    float t2 = block_reduce_sum(s2, sbuf);
    if (threadIdx.x == 0) { sc[row] = t1; tc[row] = t2; }
}

// ---- MFMA GAT aggregate: grid (D/64, T/64, B) -----------------------------
// W A-fragments computed directly in registers (exp(leaky(sc+tc)-M)); B from
// transposed hwt tile in swizzled LDS. Z per-lane, reduced xor 16/32.
__global__ __launch_bounds__(256) void gat_agg_mfma(
    const __bf16* __restrict__ hwt, const float* __restrict__ sc,
    const float* __restrict__ tc, __bf16* __restrict__ hg, int T, int D)
{
    __shared__ __bf16 Hs[64 * 64];
    __shared__ float tcs[1024];
    __shared__ float red[4];
    __shared__ float zsh[64];

    int d0 = blockIdx.x * 64, t0 = blockIdx.y * 64, b = blockIdx.z;
    int tid = threadIdx.x;
    int w = tid >> 6, lane = tid & 63, fr = lane & 15, fs = lane >> 4;

    for (int i = tid; i < T; i += 256) tcs[i] = tc[(size_t)b * T + i];
    __syncthreads();
    float lm = -1e30f;
    for (int i = tid; i < T; i += 256) lm = fmaxf(lm, tcs[i]);
    for (int off = 32; off; off >>= 1) lm = fmaxf(lm, __shfl_down(lm, off));
    if (lane == 0) red[w] = lm;
    __syncthreads();
    float tmax = fmaxf(fmaxf(red[0], red[1]), fmaxf(red[2], red[3]));

    float sct = sc[(size_t)b * T + t0 + w * 16 + fr];
    float e0 = sct + tmax;
    float Mt = e0 > 0.f ? e0 : 0.2f * e0;
    float zl = 0.f;

    f32x4_t acc[4];
    #pragma unroll
    for (int d = 0; d < 4; ++d) acc[d] = (f32x4_t){0.f, 0.f, 0.f, 0.f};

    const __bf16* hb = hwt + ((size_t)b * D + d0) * T;

    for (int s0 = 0; s0 < T; s0 += 64) {
        __syncthreads();
        #pragma unroll
        for (int i = 0; i < 2; ++i) {
            int e = tid + 256 * i; int r = e >> 3, c = e & 7;
            *(uint4*)&Hs[swz16(r, c)] = *(const uint4*)(hb + (size_t)r * T + s0 + c * 8);
        }
        __syncthreads();
        bf16x8_t af[2];
        #pragma unroll
        for (int kk = 0; kk < 2; ++kk) {
            PK4 pk;
            #pragma unroll
            for (int j = 0; j < 8; ++j) {
                float e = sct + tcs[s0 + kk * 32 + fs * 8 + j];
                e = e > 0.f ? e : 0.2f * e;
                float p = __expf(e - Mt);
                zl += p;
                pk.h[j] = (__bf16)p;
            }
            af[kk] = pk.v;
        }
        #pragma unroll
        for (int d = 0; d < 4; ++d) {
            bf16x8_t b0 = *(bf16x8_t*)&Hs[swz16(d * 16 + fr, fs)];
            bf16x8_t b1 = *(bf16x8_t*)&Hs[swz16(d * 16 + fr, 4 + fs)];
            acc[d] = __builtin_amdgcn_mfma_f32_16x16x32_bf16(af[0], b0, acc[d], 0, 0, 0);
            acc[d] = __builtin_amdgcn_mfma_f32_16x16x32_bf16(af[1], b1, acc[d], 0, 0, 0);
        }
    }
    zl += __shfl_xor(zl, 16);
    zl += __shfl_xor(zl, 32);
    if (lane < 16) zsh[w * 16 + fr] = zl;
    __syncthreads();
    #pragma unroll
    for (int r_ = 0; r_ < 4; ++r_) {
        float invz = 1.0f / zsh[w * 16 + fs * 4 + r_];
        int row = t0 + w * 16 + fs * 4 + r_;
        #pragma unroll
        for (int d = 0; d < 4; ++d)
            hg[((size_t)b * T + row) * D + d0 + d * 16 + fr] = (__bf16)(acc[d][r_] * invz);
    }
}

// ---- gated fusion: x2 = x + a*hp + (1-a)*hg (hp,hg bf16) ------------------
__global__ __launch_bounds__(256) void fuse_kernel(
    const float* __restrict__ x, const __bf16* __restrict__ hp,
    const __bf16* __restrict__ hg, const float* __restrict__ gate,
    float* __restrict__ x2, int n8)
{
    int i = blockIdx.x * 256 + threadIdx.x;
    if (i >= n8) return;
    float a = 1.0f / (1.0f + __expf(-gate[0]));
    float om = 1.0f - a;
    PK4 p, g;
    p.u = *(const uint4*)(hp + (size_t)i * 8);
    g.u = *(const uint4*)(hg + (size_t)i * 8);
    const float4* xv = (const float4*)(x + (size_t)i * 8);
    float4* ov = (float4*)(x2 + (size_t)i * 8);
    float4 x0 = xv[0], x1 = xv[1], o0, o1;
    o0.x = x0.x + a * (float)p.h[0] + om * (float)g.h[0];
    o0.y = x0.y + a * (float)p.h[1] + om * (float)g.h[1];
    o0.z = x0.z + a * (float)p.h[2] + om * (float)g.h[2];
    o0.w = x0.w + a * (float)p.h[3] + om * (float)g.h[3];
    o1.x = x1.x + a * (float)p.h[4] + om * (float)g.h[4];
    o1.y = x1.y + a * (float)p.h[5] + om * (float)g.h[5];
    o1.z = x1.z + a * (float)p.h[6] + om * (float)g.h[6];
    o1.w = x1.w + a * (float)p.h[7] + om * (float)g.h[7];
    ov[0] = o0; ov[1] = o1;
}

// ---------------------------------------------------------------------------
extern "C" void kernel_launch(void* const* d_in, const int* in_sizes, int n_in,
                              void* d_out, int out_size, void* d_ws, size_t ws_size,
                              hipStream_t stream) {
    const float* x      = (const float*)d_in[0];
    const float* Wq     = (const float*)d_in[1];
    const float* bq     = (const float*)d_in[2];
    const float* Wk     = (const float*)d_in[3];
    const float* bk     = (const float*)d_in[4];
    const float* Wv     = (const float*)d_in[5];
    const float* bv     = (const float*)d_in[6];
    const float* Wo     = (const float*)d_in[7];
    const float* bo     = (const float*)d_in[8];
    const float* interw = (const float*)d_in[9];
    const float* Wg     = (const float*)d_in[10];
    const float* a_src  = (const float*)d_in[11];
    const float* a_dst  = (const float*)d_in[12];
    const float* g1     = (const float*)d_in[13];
    const float* b1     = (const float*)d_in[14];
    const float* g2     = (const float*)d_in[15];
    const float* b2     = (const float*)d_in[16];
    const float* g3     = (const float*)d_in[17];
    const float* b3     = (const float*)d_in[18];
    const float* gate   = (const float*)d_in[19];
    const float* W1     = (const float*)d_in[20];
    const float* bf1    = (const float*)d_in[21];
    const float* W2     = (const float*)d_in[22];
    const float* bf2    = (const float*)d_in[23];

    const int D   = in_sizes[2];           // 1024
    const int BT  = in_sizes[0] / D;       // 2048
    const int T   = 1024;
    const int B   = BT / T;                // 2
    const int H   = 16;
    const int Dff = in_sizes[21];          // 4096

    const size_t MB = 1024 * 1024;
    char* wsb = (char*)d_ws;
    float*  h1  = (float*)(wsb + 0 * MB);     // 8 MB   (later x2)
    float*  h2  = (float*)(wsb + 8 * MB);     // 8 MB   (later hf)
    __bf16* qb  = (__bf16*)(wsb + 16 * MB);   // 4 MB   (later hw)
    __bf16* kb  = (__bf16*)(wsb + 20 * MB);   // 4 MB   (later hwt)
    __bf16* vb  = (__bf16*)(wsb + 24 * MB);   // 4 MB   (later ao / hg)
    __bf16* vt  = (__bf16*)(wsb + 28 * MB);   // 4 MB   (later hp)
    __bf16* ao  = (__bf16*)(wsb + 24 * MB);   // over vb (dead after transpose)
    __bf16* hp  = (__bf16*)(wsb + 28 * MB);   // over vt (dead after attn)
    __bf16* hw  = (__bf16*)(wsb + 16 * MB);   // over qb (dead after attn)
    __bf16* hwt = (__bf16*)(wsb + 20 * MB);   // over kb
    __bf16* hg  = (__bf16*)(wsb + 24 * MB);   // over ao (dead after Wo gemm)
    float*  x2  = (float*)(wsb + 0 * MB);     // over h1
    float*  hf  = (float*)(wsb + 8 * MB);     // over h2
    __bf16* mid = (__bf16*)(wsb + 32 * MB);   // 16 MB
    float*  scb = (float*)(wsb + 48 * MB);
    float*  tcb = scb + BT;

    dim3 blk(256);
    dim3 gD(D / GBN, BT / GBM);            // (16,16)
    dim3 gF(Dff / GBN, BT / GBM);          // (64,16)
    dim3 gT(T / 64, D / 64, B);

    // LN branches
    ln_kernel<<<BT, blk, 0, stream>>>(x, g1, b1, h1, D);
    ln_kernel<<<BT, blk, 0, stream>>>(x, g2, b2, h2, D);

    // QKV projections (bf16 out)
    gemm_mfma<false, true, false><<<gD, blk, 0, stream>>>(h1, Wq, bq, nullptr, qb, BT, D, D);
    gemm_mfma<false, true, false><<<gD, blk, 0, stream>>>(h1, Wk, bk, nullptr, kb, BT, D, D);
    gemm_mfma<false, true, false><<<gD, blk, 0, stream>>>(h1, Wv, bv, nullptr, vb, BT, D, D);

    // V transpose, MFMA attention, Wo projection
    transpose_bf16_64<<<gT, blk, 0, stream>>>(vb, vt, T, D);
    attn_mfma<<<dim3(T / 64, H, B), blk, 0, stream>>>(qb, kb, vt, interw, ao, T, H);
    gemm_mfma<true, true, false><<<gD, blk, 0, stream>>>(ao, Wo, bo, nullptr, hp, BT, D, D);

    // GAT branch
    gemm_mfma<false, true, false><<<gD, blk, 0, stream>>>(h2, Wg, nullptr, nullptr, hw, BT, D, D);
    gat_coeff_kernel<<<BT, blk, 0, stream>>>(hw, a_src, a_dst, scb, tcb, D);
    transpose_bf16_64<<<gT, blk, 0, stream>>>(hw, hwt, T, D);
    gat_agg_mfma<<<dim3(D / 64, T / 64, B), blk, 0, stream>>>(hwt, scb, tcb, hg, T, D);

    // gated fusion + FFN
    int n8 = (int)((size_t)BT * D / 8);
    fuse_kernel<<<(n8 + 255) / 256, blk, 0, stream>>>(x, hp, hg, gate, x2, n8);
    ln_kernel<<<BT, blk, 0, stream>>>(x2, g3, b3, hf, D);
    gemm_mfma<false, true, true><<<gF, blk, 0, stream>>>(hf, W1, bf1, nullptr, mid, BT, Dff, D);
    gemm_mfma<true, false, false><<<gD, blk, 0, stream>>>(mid, W2, bf2, x2, d_out, BT, D, Dff);
}